// Round 9
// baseline (169.823 us; speedup 1.0000x reference)
//
#include <hip/hip_runtime.h>

#define LSZ 1024
#define EPS 1e-8f
#define NBLK 1024
#define SPT 4                       // sites per thread; NBLK*256*SPT == L*L exactly
#define TSTRIDE (NBLK * 256)        // 262144 threads

typedef float vfloat4 __attribute__((ext_vector_type(4)));

struct c32 { float re, im; };

__device__ __forceinline__ c32 cmul(c32 a, c32 b) {
    return { a.re * b.re - a.im * b.im, a.re * b.im + a.im * b.re };
}
// a * conj(b)
__device__ __forceinline__ c32 cmulc(c32 a, c32 b) {
    return { a.re * b.re + a.im * b.im, a.im * b.re - a.re * b.im };
}
__device__ __forceinline__ c32 cadd(c32 a, c32 b) {
    return { a.re + b.re, a.im + b.im };
}

// g = cos(n) I + i sinc(n) (theta . sigma). Native sin/cos/rcp: theta norms
// are <= ~7 (3 gaussians), safely in fast range; error ~1e-6 << 8e-2 thresh.
__device__ __forceinline__ void make_g(float tx, float ty, float tz, c32 g[2][2]) {
    float n2 = tx * tx + ty * ty + tz * tz;
    float n  = __builtin_amdgcn_sqrtf(n2);
    float cc = __cosf(n);
    float sn = __sinf(n);
    float s  = (n > EPS) ? (sn * __builtin_amdgcn_rcpf(n)) : 1.0f;
    float a1 = s * tx, a2 = s * ty, a3 = s * tz;
    g[0][0] = {  cc,  a3 };
    g[0][1] = {  a2,  a1 };
    g[1][0] = { -a2,  a1 };
    g[1][1] = {  cc, -a3 };
}

// Ut = g @ M @ gn^dagger ; return sum |P - Ut|^2 over the 4 entries
__device__ __forceinline__ float site_mu_loss(const c32 g[2][2], const c32 gn[2][2],
                                              vfloat4 m0, vfloat4 m1,
                                              vfloat4 p0, vfloat4 p1) {
    c32 M[2][2] = { { { m0.x, m0.y }, { m0.z, m0.w } },
                    { { m1.x, m1.y }, { m1.z, m1.w } } };
    c32 P[2][2] = { { { p0.x, p0.y }, { p0.z, p0.w } },
                    { { p1.x, p1.y }, { p1.z, p1.w } } };
    c32 T[2][2];
#pragma unroll
    for (int a = 0; a < 2; ++a)
#pragma unroll
        for (int cc = 0; cc < 2; ++cc)
            T[a][cc] = cadd(cmul(g[a][0], M[0][cc]), cmul(g[a][1], M[1][cc]));

    float acc = 0.0f;
#pragma unroll
    for (int a = 0; a < 2; ++a)
#pragma unroll
        for (int d = 0; d < 2; ++d) {
            c32 ut = cadd(cmulc(T[a][0], gn[d][0]), cmulc(T[a][1], gn[d][1]));
            float dr = P[a][d].re - ut.re;
            float di = P[a][d].im - ut.im;
            acc += dr * dr + di * di;
        }
    return acc;
}

// Full payload for one site, held in REGISTERS (41 dwords). All member access
// is static -> SROA into VGPRs (no scratch, rule #20).
struct Pay {
    vfloat4 t0, t1, t2, t3;     // U_true[mu=0,1]
    vfloat4 p0, p1, p2, p3;     // U_pred[mu=0,1]
    float a0, a1, a2;           // theta(x,y)
    float b0, b1, b2;           // theta(x+1,y)
    float c0, c1, c2;           // theta(x,y+1)
};

// NT-REG-DEEP variant (R9). Matrix so far: temporal/any-depth = 1.5-1.65 TB/s
// (dirty-L3 victim interleave); NT+shallow(VGPR, R6) = 2.36 TB/s (depth-capped
// exactly at latency-BW product); NT+deep(LDS-DMA, R8) ~ 2.7-3.2 TB/s. The bus
// itself does 6.5 TB/s (poison fills). Last untested cell: NT + deep + VGPR
// destination (the LDS-DMA return path may be the throttle). R2's failed
// batching is explained: 28-reg budget + "+v" value-fences FORCED a waitcnt
// (any use of a load result waits) -- here the batch fits (launch_bounds
// (256,4) = 128 VGPR) and sched_barrier(0) pins issue order WITHOUT forcing a
// wait. A/B payloads alternate: B's 17 NT loads issue before A's compute; the
// compiler's hazard waitcnt on A's first use leaves B's loads in flight.
// 16 waves/CU x ~10.5 KB in flight >> 22 KB/CU latency-BW product.
// theta is TEMPORAL (3x reuse via L2/L3; NT would forfeit it), U is NT.
__device__ __forceinline__ void load_site(int idx,
                                          const float* __restrict__ theta,
                                          const float* __restrict__ U_pred,
                                          const float* __restrict__ U_true,
                                          Pay& P) {
    const int x = idx >> 10, y = idx & (LSZ - 1);
    const int xp = (x + 1) & (LSZ - 1), yp = (y + 1) & (LSZ - 1);
    const vfloat4* Ut4 = (const vfloat4*)U_true + (size_t)idx * 4;
    const vfloat4* Up4 = (const vfloat4*)U_pred + (size_t)idx * 4;
    P.t0 = __builtin_nontemporal_load(Ut4);
    P.t1 = __builtin_nontemporal_load(Ut4 + 1);
    P.t2 = __builtin_nontemporal_load(Ut4 + 2);
    P.t3 = __builtin_nontemporal_load(Ut4 + 3);
    P.p0 = __builtin_nontemporal_load(Up4);
    P.p1 = __builtin_nontemporal_load(Up4 + 1);
    P.p2 = __builtin_nontemporal_load(Up4 + 2);
    P.p3 = __builtin_nontemporal_load(Up4 + 3);
    const float* ta = theta + 3 * (x  * LSZ + y);
    const float* tb = theta + 3 * (xp * LSZ + y);
    const float* tc = theta + 3 * (x  * LSZ + yp);
    P.a0 = ta[0]; P.a1 = ta[1]; P.a2 = ta[2];       // temporal: 3x reuse
    P.b0 = tb[0]; P.b1 = tb[1]; P.b2 = tb[2];
    P.c0 = tc[0]; P.c1 = tc[1]; P.c2 = tc[2];
}

__device__ __forceinline__ float site_loss(const Pay& P) {
    c32 g[2][2], gn[2][2];
    make_g(P.a0, P.a1, P.a2, g);
    make_g(P.b0, P.b1, P.b2, gn);
    float acc = site_mu_loss(g, gn, P.t0, P.t1, P.p0, P.p1);   // mu = 0
    make_g(P.c0, P.c1, P.c2, gn);
    acc += site_mu_loss(g, gn, P.t2, P.t3, P.p2, P.p3);        // mu = 1
    return acc;
}

__global__ __launch_bounds__(256, 4) void gauge_loss_kernel(
    const float* __restrict__ theta,
    const float* __restrict__ U_pred,
    const float* __restrict__ U_true,
    float* __restrict__ partial) {
    const int tid = blockIdx.x * 256 + threadIdx.x;

    Pay A, B;
    float acc = 0.0f;

    load_site(tid, theta, U_pred, U_true, A);

    // SPT = 4, fully unrolled A/B ping-pong. sched_barrier(0) after each load
    // batch: pure scheduling boundary (no data use -> no forced waitcnt);
    // loads cannot sink below it, compute cannot hoist above it.
    load_site(tid + 1 * TSTRIDE, theta, U_pred, U_true, B);
    __builtin_amdgcn_sched_barrier(0);
    acc += site_loss(A);

    load_site(tid + 2 * TSTRIDE, theta, U_pred, U_true, A);
    __builtin_amdgcn_sched_barrier(0);
    acc += site_loss(B);

    load_site(tid + 3 * TSTRIDE, theta, U_pred, U_true, B);
    __builtin_amdgcn_sched_barrier(0);
    acc += site_loss(A);

    __builtin_amdgcn_sched_barrier(0);
    acc += site_loss(B);

    // fold: mean over 4 entries (1/4) and final /(L*L*2)
    acc *= (1.0f / (8.0f * (float)LSZ * (float)LSZ));

    // wave (64-lane) shuffle reduction
#pragma unroll
    for (int off = 32; off > 0; off >>= 1)
        acc += __shfl_down(acc, off, 64);

    __shared__ float wave_sums[4];
    int lane = threadIdx.x & 63;
    int wave = threadIdx.x >> 6;
    if (lane == 0) wave_sums[wave] = acc;
    __syncthreads();
    if (threadIdx.x == 0)
        partial[blockIdx.x] = wave_sums[0] + wave_sums[1] + wave_sums[2] + wave_sums[3];
}

__global__ __launch_bounds__(256) void reduce_kernel(const float* __restrict__ partial,
                                                     float* __restrict__ out) {
    float s = 0.0f;
#pragma unroll
    for (int i = 0; i < NBLK / 256; ++i)
        s += partial[i * 256 + threadIdx.x];

#pragma unroll
    for (int off = 32; off > 0; off >>= 1)
        s += __shfl_down(s, off, 64);

    __shared__ float wave_sums[4];
    int lane = threadIdx.x & 63;
    int wave = threadIdx.x >> 6;
    if (lane == 0) wave_sums[wave] = s;
    __syncthreads();
    if (threadIdx.x == 0)
        out[0] = wave_sums[0] + wave_sums[1] + wave_sums[2] + wave_sums[3];
}

extern "C" void kernel_launch(void* const* d_in, const int* in_sizes, int n_in,
                              void* d_out, int out_size, void* d_ws, size_t ws_size,
                              hipStream_t stream) {
    const float* theta  = (const float*)d_in[0];
    const float* U_pred = (const float*)d_in[1];
    const float* U_true = (const float*)d_in[2];
    float* out = (float*)d_out;
    float* partial = (float*)d_ws;  // NBLK floats

    gauge_loss_kernel<<<NBLK, 256, 0, stream>>>(theta, U_pred, U_true, partial);
    reduce_kernel<<<1, 256, 0, stream>>>(partial, out);
}

// Round 10
// 147.271 us; speedup vs baseline: 1.1531x; 1.1531x over previous
//
#include <hip/hip_runtime.h>

#define LSZ 1024
#define EPS 1e-8f
#define NBLK 512
#define SPT 8                       // phases per thread; NBLK*256*SPT == L*L exactly
#define TSTRIDE (NBLK * 256)        // 131072 threads

// gfx950 CPol bits: bit0=sc0, bit1=nt, bit4=sc1.
// R8 (aux=2, nt) = best so far (~39 us, 2.8 TB/s). R10 tests full scope
// bypass: sc0|nt|sc1 = 19 -> system-scope streaming load, bypasses per-XCD
// TCC allocation/victim machinery (suspected cold-read throttle after the
// harness's 268 MB poison fill). Correctness-safe: MALL is memory-side
// (always coherent); host upload never dirties XCD L2.
#define CPOL_U 19
#define CPOL_NT 2

typedef float vfloat4 __attribute__((ext_vector_type(4)));

#define AS1 __attribute__((address_space(1)))
#define AS3 __attribute__((address_space(3)))

struct c32 { float re, im; };

__device__ __forceinline__ c32 cmul(c32 a, c32 b) {
    return { a.re * b.re - a.im * b.im, a.re * b.im + a.im * b.re };
}
// a * conj(b)
__device__ __forceinline__ c32 cmulc(c32 a, c32 b) {
    return { a.re * b.re + a.im * b.im, a.im * b.re - a.re * b.im };
}
__device__ __forceinline__ c32 cadd(c32 a, c32 b) {
    return { a.re + b.re, a.im + b.im };
}

// g = cos(n) I + i sinc(n) (theta . sigma). Native sin/cos/rcp: theta norms
// are <= ~7 (3 gaussians), safely in fast range; error ~1e-6 << 8e-2 thresh.
__device__ __forceinline__ void make_g(float tx, float ty, float tz, c32 g[2][2]) {
    float n2 = tx * tx + ty * ty + tz * tz;
    float n  = __builtin_amdgcn_sqrtf(n2);
    float cc = __cosf(n);
    float sn = __sinf(n);
    float s  = (n > EPS) ? (sn * __builtin_amdgcn_rcpf(n)) : 1.0f;
    float a1 = s * tx, a2 = s * ty, a3 = s * tz;
    g[0][0] = {  cc,  a3 };
    g[0][1] = {  a2,  a1 };
    g[1][0] = { -a2,  a1 };
    g[1][1] = {  cc, -a3 };
}

// Ut = g @ M @ gn^dagger ; return sum |P - Ut|^2 over the 4 entries
__device__ __forceinline__ float site_mu_loss(const c32 g[2][2], const c32 gn[2][2],
                                              vfloat4 m0, vfloat4 m1,
                                              vfloat4 p0, vfloat4 p1) {
    c32 M[2][2] = { { { m0.x, m0.y }, { m0.z, m0.w } },
                    { { m1.x, m1.y }, { m1.z, m1.w } } };
    c32 P[2][2] = { { { p0.x, p0.y }, { p0.z, p0.w } },
                    { { p1.x, p1.y }, { p1.z, p1.w } } };
    c32 T[2][2];
#pragma unroll
    for (int a = 0; a < 2; ++a)
#pragma unroll
        for (int cc = 0; cc < 2; ++cc)
            T[a][cc] = cadd(cmul(g[a][0], M[0][cc]), cmul(g[a][1], M[1][cc]));

    float acc = 0.0f;
#pragma unroll
    for (int a = 0; a < 2; ++a)
#pragma unroll
        for (int d = 0; d < 2; ++d) {
            c32 ut = cadd(cmulc(T[a][0], gn[d][0]), cmulc(T[a][1], gn[d][1]));
            float dr = P[a][d].re - ut.re;
            float di = P[a][d].im - ut.im;
            acc += dr * dr + di * di;
        }
    return acc;
}

// BYPASS-DMA variant (R10). Evidence matrix: temporal/any-depth 1.5-1.65 TB/s;
// NT+shallow-VGPR 2.36 (exactly latency-BW-capped); NT+reg-medium 2.0 (VGPR=64,
// compiler refuses big reg batches -- 3rd confirmation); NT+LDS-DMA-deep 2.8
// TB/s, ~39 us, with 64 KB/CU in flight >> 22 KB product -> depth saturated,
// policy is the residual axis. The fills do 6.5 TB/s through the same bus, so
// the cap is in the allocating path -- suspect: TCC (per-XCD L2) miss/victim
// machinery right after 268 MB of poison writes. sc1 makes loads system-scope
// (L2-bypass); nt suppresses MALL allocation churn. Structure = R8 verbatim.
//
// gload_lds writes LINEAR (base + lane*16, rule #21), so the bank swizzle is
// applied on the GLOBAL source: involution f(c) = c ^ ((c>>3)&7) on 16B-chunk
// index. Reader (thread t, quarter q) wants chunk c=4t+q -> slot f(c); read
// residues mod 8 uniform = ds_read_b128 conflict-free floor. Verified R7/R8.
__global__ __launch_bounds__(256, 2) void gauge_loss_kernel(
    const float* __restrict__ theta,
    const float* __restrict__ U_pred,
    const float* __restrict__ U_true,
    float* __restrict__ partial) {
    // [wave][buf][arr: 0=U_true 1=U_pred][1024 floats = 4 KB]  -> 64 KB total
    __shared__ __align__(16) float lds[4][2][2][1024];
    const int tid  = blockIdx.x * 256 + threadIdx.x;
    const int lane = threadIdx.x & 63;
    const int wv   = threadIdx.x >> 6;
    const int lswz = lane ^ ((lane >> 3) & 7);          // writer-side source swizzle

    // ---- stage: issue 8 global_load_lds (4 KB U_true + 4 KB U_pred) ----
    auto STAGE = [&](int p, int b) {
        const size_t wbase = (size_t)(tid - lane) + (size_t)p * TSTRIDE;
        const char* gT = (const char*)U_true + wbase * 64;
        const char* gP = (const char*)U_pred + wbase * 64;
#pragma unroll
        for (int k = 0; k < 4; ++k) {
            const int c = k * 64 + lswz;                // chunk this lane fetches
            __builtin_amdgcn_global_load_lds(
                (const AS1 void*)(gT + (size_t)c * 16),
                (AS3 void*)((char*)&lds[wv][b][0][0] + k * 1024), 16, 0, CPOL_U);
            __builtin_amdgcn_global_load_lds(
                (const AS1 void*)(gP + (size_t)c * 16),
                (AS3 void*)((char*)&lds[wv][b][1][0] + k * 1024), 16, 0, CPOL_U);
        }
    };

    STAGE(0, 0);

    float acc = 0.0f;
#pragma unroll
    for (int p = 0; p < SPT; ++p) {
        const int site = tid + p * TSTRIDE;
        const int x = site >> 10, y = site & (LSZ - 1);
        const int xp = (x + 1) & (LSZ - 1), yp = (y + 1) & (LSZ - 1);
        // theta loads issued BEFORE next stage: queue = [stage_p(8), theta,
        // stage_{p+1}(8)] -> vmcnt(8) drains stage_p + theta, keeps stage_{p+1}.
        const float* ta = theta + 3 * (x  * LSZ + y);
        const float* tb = theta + 3 * (xp * LSZ + y);
        const float* tc = theta + 3 * (x  * LSZ + yp);
        float a0 = __builtin_nontemporal_load(ta);
        float a1 = __builtin_nontemporal_load(ta + 1);
        float a2 = __builtin_nontemporal_load(ta + 2);
        float b0 = __builtin_nontemporal_load(tb);
        float b1 = __builtin_nontemporal_load(tb + 1);
        float b2 = __builtin_nontemporal_load(tb + 2);
        float c0 = __builtin_nontemporal_load(tc);
        float c1 = __builtin_nontemporal_load(tc + 1);
        float c2 = __builtin_nontemporal_load(tc + 2);
        __builtin_amdgcn_sched_barrier(0);

        if (p + 1 < SPT) STAGE(p + 1, (p + 1) & 1);
        __builtin_amdgcn_sched_barrier(0);
        if (p + 1 < SPT) asm volatile("s_waitcnt vmcnt(8)" ::: "memory");
        else             asm volatile("s_waitcnt vmcnt(0)" ::: "memory");
        __builtin_amdgcn_sched_barrier(0);

        // ---- swizzled LDS readback: 4x ds_read_b128 per array ----
        const float* lT = &lds[wv][p & 1][0][0];
        const float* lP = &lds[wv][p & 1][1][0];
        vfloat4 t[4], pr[4];
#pragma unroll
        for (int q = 0; q < 4; ++q) {
            const int c = 4 * lane + q;
            const int s = c ^ ((c >> 3) & 7);           // slot holding chunk c
            t[q]  = *(const vfloat4*)(lT + 4 * s);
            pr[q] = *(const vfloat4*)(lP + 4 * s);
        }

        c32 g[2][2], gn[2][2];
        make_g(a0, a1, a2, g);
        make_g(b0, b1, b2, gn);
        acc += site_mu_loss(g, gn, t[0], t[1], pr[0], pr[1]);   // mu = 0
        make_g(c0, c1, c2, gn);
        acc += site_mu_loss(g, gn, t[2], t[3], pr[2], pr[3]);   // mu = 1
    }

    // fold: mean over 4 entries (1/4) and final /(L*L*2)
    acc *= (1.0f / (8.0f * (float)LSZ * (float)LSZ));

    // wave (64-lane) shuffle reduction
#pragma unroll
    for (int off = 32; off > 0; off >>= 1)
        acc += __shfl_down(acc, off, 64);

    __shared__ float wave_sums[4];
    if (lane == 0) wave_sums[wv] = acc;
    __syncthreads();
    if (threadIdx.x == 0)
        partial[blockIdx.x] = wave_sums[0] + wave_sums[1] + wave_sums[2] + wave_sums[3];
}

__global__ __launch_bounds__(256) void reduce_kernel(const float* __restrict__ partial,
                                                     float* __restrict__ out) {
    float s = 0.0f;
#pragma unroll
    for (int i = 0; i < NBLK / 256; ++i)
        s += partial[i * 256 + threadIdx.x];

#pragma unroll
    for (int off = 32; off > 0; off >>= 1)
        s += __shfl_down(s, off, 64);

    __shared__ float wave_sums[4];
    int lane = threadIdx.x & 63;
    int wave = threadIdx.x >> 6;
    if (lane == 0) wave_sums[wave] = s;
    __syncthreads();
    if (threadIdx.x == 0)
        out[0] = wave_sums[0] + wave_sums[1] + wave_sums[2] + wave_sums[3];
}

extern "C" void kernel_launch(void* const* d_in, const int* in_sizes, int n_in,
                              void* d_out, int out_size, void* d_ws, size_t ws_size,
                              hipStream_t stream) {
    const float* theta  = (const float*)d_in[0];
    const float* U_pred = (const float*)d_in[1];
    const float* U_true = (const float*)d_in[2];
    float* out = (float*)d_out;
    float* partial = (float*)d_ws;  // NBLK floats

    gauge_loss_kernel<<<NBLK, 256, 0, stream>>>(theta, U_pred, U_true, partial);
    reduce_kernel<<<1, 256, 0, stream>>>(partial, out);
}